// Round 5
// baseline (129.308 us; speedup 1.0000x reference)
//
#include <hip/hip_runtime.h>
#include <hip/hip_bf16.h>

#define B_ 4
#define N_ 4096
#define D_ 128
#define EPB (N_ * D_)        // BYTES per batch in packed fp8 layout = 524288
#define COFF 1024.0f         // colmin positivity offset

typedef float f32x4 __attribute__((ext_vector_type(4)));
typedef int   int8v __attribute__((ext_vector_type(8)));
typedef int   int4v __attribute__((ext_vector_type(4)));

#define SQRT2 1.41421356237309515f

// ---------------------------------------------------------------------------
// Packed K-major fp8 layout (per batch, BYTE addresses):
//   elem(row, k) -> (row>>4)*2048 + (k>>5)*512 + (row&15)*32 + (k&31)
// K=128 MFMA fragment (16x16x128 f8f6f4): lane (quad,l16): row = l16,
// k = quad*32 + j  ->  32 CONTIGUOUS bytes at rg*2048 + quad*512 + l16*32.
// Register order (k monotone in reg index) verified on HW (R9/R10, absmax 0).
// REGISTER CLIFF LOG:
//   R5/R9/R11: extra live arrays / fused tails -> spill (WRITE_SIZE ~90MB).
//   R12: rotation + acc=-y2 init -> spill (76.8MB), 132us.
//   R13: acc=-y2 init ALONE -> spill (89MB). DIAGNOSIS CONFIRMED: computed-
//        value acc init forces acc into arch VGPRs; inline-ZERO init keeps
//        acc in the AGPR half (arch <=128, clean). RULE: acc zero-init only;
//        fold consumes y2v (R10 style).
//   R14: half tile acc[4][2], 2x blocks -> clean but 101us (latency-bound:
//        doubled per-block serial prologue/epilogue costs). REVERTED.
// R15: R0 tile + bfv ROTATION ONLY (never tested in isolation): next step's
// B-fragment loads issued right after the MFMA burst, landing under the
// ~600-cyc fold+atomics. y2v loads stay at step top (consumed only by fold;
// MFMA burst covers their latency). Zero extra live registers by design.
// ---------------------------------------------------------------------------

// Kernel 1: fp32 -> fp8 e4m3 (*sqrt2) into packed layout + row norms + min
// init. Thread t: row r = t>>4 (in group), k-chunk c = t&15 -> consecutive
// lanes read consecutive 32 B (fully coalesced). Norm: 4 in-group shuffles.
__global__ __launch_bounds__(256) void prep_kernel(
    const float* __restrict__ X, const float* __restrict__ Y,
    unsigned char* __restrict__ Xb, unsigned char* __restrict__ Yb,
    float* __restrict__ x2, float* __restrict__ y2,
    int* __restrict__ rowmin, int* __restrict__ colmin)
{
    const int which = blockIdx.y;
    const float* __restrict__ src = which ? Y : X;
    unsigned char* __restrict__ dst = which ? Yb : Xb;
    float* __restrict__ nrm = which ? y2 : x2;
    int* __restrict__ mn = which ? colmin : rowmin;

    const int t = threadIdx.x;
    const int r = t >> 4, c = t & 15;          // r,c in 0..15
    const int rgG = blockIdx.x;                // global row-group
    const int row = rgG * 16 + r;

    const float4 v0 = *(const float4*)(src + (size_t)row * D_ + c * 8);
    const float4 v1 = *(const float4*)(src + (size_t)row * D_ + c * 8 + 4);

    float sq = v0.x * v0.x;
    sq = fmaf(v0.y, v0.y, sq); sq = fmaf(v0.z, v0.z, sq); sq = fmaf(v0.w, v0.w, sq);
    sq = fmaf(v1.x, v1.x, sq); sq = fmaf(v1.y, v1.y, sq);
    sq = fmaf(v1.z, v1.z, sq); sq = fmaf(v1.w, v1.w, sq);
    // reduce across the 16 lanes of this row (xor masks stay in-group)
    #pragma unroll
    for (int m = 1; m < 16; m <<= 1) sq += __shfl_xor(sq, m);

    unsigned lo = 0, hi = 0;
    lo = __builtin_amdgcn_cvt_pk_fp8_f32(v0.x * SQRT2, v0.y * SQRT2, lo, false);
    lo = __builtin_amdgcn_cvt_pk_fp8_f32(v0.z * SQRT2, v0.w * SQRT2, lo, true);
    hi = __builtin_amdgcn_cvt_pk_fp8_f32(v1.x * SQRT2, v1.y * SQRT2, hi, false);
    hi = __builtin_amdgcn_cvt_pk_fp8_f32(v1.z * SQRT2, v1.w * SQRT2, hi, true);

    const int b = row >> 12;
    const int rg = (row & (N_ - 1)) >> 4;
    uint2 packed; packed.x = lo; packed.y = hi;
    // k = c*8:  (k>>5) = c>>2,  (k&31) = (c&3)*8
    *(uint2*)(dst + (size_t)b * EPB + rg * 2048 + (c >> 2) * 512
              + r * 32 + (c & 3) * 8) = packed;

    if (c == 0) {
        nrm[row] = sq;
        mn[row] = 0x7f7fffff;   // +FLT_MAX bits
    }
}

// ---------------------------------------------------------------------------
// Kernel 2: stripe-sweep MX-fp8 (K=128) MFMA chamfer. NO LDS, NO barriers.
// Block = 4 waves x 64 distinct rows = 256-row stripe (grid y = 16).
// Sweeps 4 steps of 64 cols (jc = 256-col chunk, grid x = 16).
// 16 K=128 MFMAs per step, e8m0 scale 127 = x1.0 (== non-scaled fp8).
//   acc == 2*zz (inputs pre-scaled by sqrt2); P = x2 + y2 - acc.
//   C/D layout: row = quad*4 + reg, col = l16   [m89; shape-determined]
// acc ZERO-INIT (AGPR placement rule — see cliff log). R10 fold:
//   rm = min(rm, y2 - acc);  cm = min(cm, x2 - acc).
// R15: bfv prefetch rotated to after the MFMA burst (s+1 fragments land
// under the fold); y2v loads stay at step top.
// ---------------------------------------------------------------------------
__global__ __launch_bounds__(256, 2) void chamfer_mfma(
    const unsigned char* __restrict__ Xb, const unsigned char* __restrict__ Yb,
    const float* __restrict__ x2, const float* __restrict__ y2,
    int* __restrict__ rowmin, int* __restrict__ colmin)
{
    const int b = blockIdx.z;
    const int iT = blockIdx.y;           // 0..15  (256-row stripe)
    const int jc = blockIdx.x;           // 0..15  (256-col chunk)
    const int tid = threadIdx.x;
    const int wave = tid >> 6, lane = tid & 63;
    const int quad = lane >> 4, l16 = lane & 15;
    const int rowBase = iT * 256 + wave * 64;

    const unsigned char* __restrict__ Xp = Xb + (size_t)b * EPB;
    const unsigned char* __restrict__ Yp = Yb + (size_t)b * EPB;

    // ---- A fragments resident (4 x v8i32 = 32 VGPR), register-only build ----
    int8v af[4];
    #pragma unroll
    for (int rt = 0; rt < 4; rt++) {
        const unsigned char* ap = Xp + ((rowBase >> 4) + rt) * 2048
                                 + quad * 512 + l16 * 32;
        const int4v lo = *(const int4v*)(ap);
        const int4v hi = *(const int4v*)(ap + 16);
        af[rt] = (int8v){lo.x, lo.y, lo.z, lo.w, hi.x, hi.y, hi.z, hi.w};
    }
    float x2v[4][4];   // row = rowBase + rt*16 + quad*4 + i
    #pragma unroll
    for (int rt = 0; rt < 4; rt++)
        #pragma unroll
        for (int i = 0; i < 4; i++)
            x2v[rt][i] = x2[(size_t)b * N_ + rowBase + rt * 16 + quad * 4 + i];

    float rmin[4][4];
    #pragma unroll
    for (int rt = 0; rt < 4; rt++)
        #pragma unroll
        for (int i = 0; i < 4; i++) rmin[rt][i] = 3.0e38f;

    // ---- step-0 B-fragment prefetch (single buffer, overwritten in-loop) ----
    int8v bfv[4];
    {
        const int cg0 = (jc * 256) >> 4;
        #pragma unroll
        for (int ct = 0; ct < 4; ct++) {
            const unsigned char* bp = Yp + (size_t)(cg0 + ct) * 2048
                                     + quad * 512 + l16 * 32;
            const int4v lo = *(const int4v*)(bp);
            const int4v hi = *(const int4v*)(bp + 16);
            bfv[ct] = (int8v){lo.x, lo.y, lo.z, lo.w, hi.x, hi.y, hi.z, hi.w};
        }
    }

    #pragma unroll
    for (int s = 0; s < 4; ++s) {
        const int colBase = jc * 256 + s * 64;

        // y2v at step top: consumed only by the fold, so the MFMA burst
        // covers its latency. 4 scalar regs, dies at end of fold.
        float y2v[4];
        #pragma unroll
        for (int ct = 0; ct < 4; ct++)
            y2v[ct] = y2[(size_t)b * N_ + colBase + ct * 16 + l16];

        f32x4 acc[4][4];
        #pragma unroll
        for (int i = 0; i < 4; i++)
            #pragma unroll
            for (int j = 0; j < 4; j++)
                acc[i][j] = (f32x4){0.f, 0.f, 0.f, 0.f};

        #pragma unroll
        for (int rt = 0; rt < 4; rt++)
            #pragma unroll
            for (int ct = 0; ct < 4; ct++)
                acc[rt][ct] = __builtin_amdgcn_mfma_scale_f32_16x16x128_f8f6f4(
                    af[rt], bfv[ct], acc[rt][ct],
                    0, 0,          // cbsz = fp8 e4m3 (A), blgp = fp8 e4m3 (B)
                    0, 127,        // scale A: e8m0 127 = 1.0
                    0, 127);       // scale B: e8m0 127 = 1.0

        // ---- rotated prefetch: next step's B fragments land under the fold.
        // bfv is dead after the burst above; same registers, no extra live.
        if (s < 3) {
            const int cgN = (colBase + 64) >> 4;
            #pragma unroll
            for (int ct = 0; ct < 4; ct++) {
                const unsigned char* bp = Yp + (size_t)(cgN + ct) * 2048
                                         + quad * 512 + l16 * 32;
                const int4v lo = *(const int4v*)(bp);
                const int4v hi = *(const int4v*)(bp + 16);
                bfv[ct] = (int8v){lo.x, lo.y, lo.z, lo.w, hi.x, hi.y, hi.z, hi.w};
            }
        }

        // ---- fold: rmin over cols (persist); cmin over rows (emit now) ----
        float cmin[4];
        #pragma unroll
        for (int ct = 0; ct < 4; ct++) cmin[ct] = 3.0e38f;
        #pragma unroll
        for (int rt = 0; rt < 4; rt++)
            #pragma unroll
            for (int i = 0; i < 4; i++) {
                const float xv = x2v[rt][i];
                float rm = rmin[rt][i];
                #pragma unroll
                for (int ct = 0; ct < 4; ct++) {
                    const float a = acc[rt][ct][i];
                    rm = fminf(rm, y2v[ct] - a);
                    cmin[ct] = fminf(cmin[ct], xv - a);
                }
                rmin[rt][i] = rm;
            }
        #pragma unroll
        for (int ct = 0; ct < 4; ct++) {
            float v = cmin[ct];
            v = fminf(v, __shfl_xor(v, 16));
            v = fminf(v, __shfl_xor(v, 32));
            if (quad == 0)
                atomicMin(&colmin[(size_t)b * N_ + colBase + ct * 16 + l16],
                          __float_as_int(v + COFF));
        }
    }

    // ---- rowmin emission (once per block) ----
    #pragma unroll
    for (int rt = 0; rt < 4; rt++)
        #pragma unroll
        for (int i = 0; i < 4; i++) {
            float v = rmin[rt][i];
            #pragma unroll
            for (int m = 1; m < 16; m <<= 1) v = fminf(v, __shfl_xor(v, m));
            if (l16 == 0) {
                float c = fminf(fmaxf(x2v[rt][i] + v, 0.0f), 100.0f);
                atomicMin(&rowmin[(size_t)b * N_ + rowBase + rt * 16 + quad * 4 + i],
                          __float_as_int(c));
            }
        }
}

// ---------------------------------------------------------------------------
// Kernel 3: final mean, single 1024-thread block, direct write.
// rowmin holds clamped values; colmin holds (min_i(x2_i - acc) + COFF):
// add y2, subtract COFF, clamp here.
// ---------------------------------------------------------------------------
__global__ __launch_bounds__(1024) void finalize_kernel(
    const int* __restrict__ rowmin, const int* __restrict__ colmin,
    const float* __restrict__ y2, float* __restrict__ out)
{
    float s = 0.f;
    for (int i = threadIdx.x; i < B_ * N_ / 4; i += 1024) {
        int4 v = ((const int4*)rowmin)[i];
        s += __int_as_float(v.x) + __int_as_float(v.y) +
             __int_as_float(v.z) + __int_as_float(v.w);
        int4 c = ((const int4*)colmin)[i];
        float4 yv = ((const float4*)y2)[i];
        s += fminf(fmaxf(__int_as_float(c.x) - COFF + yv.x, 0.f), 100.f);
        s += fminf(fmaxf(__int_as_float(c.y) - COFF + yv.y, 0.f), 100.f);
        s += fminf(fmaxf(__int_as_float(c.z) - COFF + yv.z, 0.f), 100.f);
        s += fminf(fmaxf(__int_as_float(c.w) - COFF + yv.w, 0.f), 100.f);
    }
    #pragma unroll
    for (int m = 1; m < 64; m <<= 1) s += __shfl_xor(s, m);
    __shared__ float sm[16];
    if ((threadIdx.x & 63) == 0) sm[threadIdx.x >> 6] = s;
    __syncthreads();
    if (threadIdx.x == 0) {
        float t = 0.f;
        #pragma unroll
        for (int i = 0; i < 16; i++) t += sm[i];
        out[0] = t / ((float)B_ * (float)N_) / (float)B_;
    }
}

extern "C" void kernel_launch(void* const* d_in, const int* in_sizes, int n_in,
                              void* d_out, int out_size, void* d_ws, size_t ws_size,
                              hipStream_t stream) {
    const float* X = (const float*)d_in[0];   // corr_pred   [B,N,D] fp32
    const float* Y = (const float*)d_in[1];   // corr_target [B,N,D] fp32

    char* ws = (char*)d_ws;
    const size_t f8_bytes = (size_t)B_ * N_ * D_;       // 2 MB each (packed fp8)
    unsigned char* Xb = (unsigned char*)ws;
    unsigned char* Yb = (unsigned char*)(ws + f8_bytes);
    char* ws2 = ws + 2 * f8_bytes;
    const size_t vec_bytes = (size_t)B_ * N_ * 4;       // 64 KB each
    float* x2     = (float*)(ws2);
    float* y2     = (float*)(ws2 + vec_bytes);
    int*   rowmin = (int*)  (ws2 + 2 * vec_bytes);
    int*   colmin = (int*)  (ws2 + 3 * vec_bytes);
    float* out = (float*)d_out;

    prep_kernel<<<dim3(B_ * N_ / 16, 2), 256, 0, stream>>>(
        X, Y, Xb, Yb, x2, y2, rowmin, colmin);
    chamfer_mfma<<<dim3(16, N_ / 256, B_), 256, 0, stream>>>(
        Xb, Yb, x2, y2, rowmin, colmin);
    finalize_kernel<<<1, 1024, 0, stream>>>(rowmin, colmin, y2, out);
}

// Round 6
// 90.915 us; speedup vs baseline: 1.4223x; 1.4223x over previous
//
#include <hip/hip_runtime.h>
#include <hip/hip_bf16.h>

#define B_ 4
#define N_ 4096
#define D_ 128
#define EPB (N_ * D_)        // BYTES per batch in packed fp8 layout = 524288
#define COFF 1024.0f         // colmin positivity offset

typedef float f32x4 __attribute__((ext_vector_type(4)));
typedef float f32x2 __attribute__((ext_vector_type(2)));
typedef int   int8v __attribute__((ext_vector_type(8)));
typedef int   int4v __attribute__((ext_vector_type(4)));

#define SQRT2 1.41421356237309515f

// ---------------------------------------------------------------------------
// Packed K-major fp8 layout (per batch, BYTE addresses):
//   elem(row, k) -> (row>>4)*2048 + (k>>5)*512 + (row&15)*32 + (k&31)
// K=128 MFMA fragment (16x16x128 f8f6f4): lane (quad,l16): row = l16,
// k = quad*32 + j  ->  32 CONTIGUOUS bytes at rg*2048 + quad*512 + l16*32.
// Register order (k monotone in reg index) verified on HW (R9/R10, absmax 0).
// REGISTER CLIFF LOG (complete verdict):
//   R5/R9/R11: extra live arrays / fused tails -> spill (~90MB WRITE_SIZE).
//   R12: rotation + acc=-y2 init -> spill (76.8MB).
//   R13: acc=-y2 init alone -> spill (89MB). RULE: acc must be inline-ZERO
//        init (AGPR-side placement); computed init forces arch VGPRs.
//   R15: bfv rotation alone -> spill (80.9MB). Rotated bfv lives across the
//        fold (+32 arch regs at peak). RULE: no live range may span the fold.
//   R14: acc[4][2] + DOUBLED block count -> clean but 101us (per-block fixed
//        costs doubled in a latency-bound kernel). Tile-split != block-split.
// R16: acc[4][2] ct-split WITHOUT changing the grid: same 256-col chunk,
// all 4 bfv at step top (full memory parallelism), burst+fold twice per
// step through one 32-AGPR accumulator. Unified regs ~192 -> ~160 =>
// 3 waves/SIMD schedulable (launch_bounds floor unchanged). Plus two-stage
// finalize (single-block 768KB stream was one-CU-bound).
// ---------------------------------------------------------------------------

// Kernel 1: fp32 -> fp8 e4m3 (*sqrt2) into packed layout + row norms + min
// init. Thread t: row r = t>>4 (in group), k-chunk c = t&15 -> consecutive
// lanes read consecutive 32 B (fully coalesced). Norm: 4 in-group shuffles.
__global__ __launch_bounds__(256) void prep_kernel(
    const float* __restrict__ X, const float* __restrict__ Y,
    unsigned char* __restrict__ Xb, unsigned char* __restrict__ Yb,
    float* __restrict__ x2, float* __restrict__ y2,
    int* __restrict__ rowmin, int* __restrict__ colmin)
{
    const int which = blockIdx.y;
    const float* __restrict__ src = which ? Y : X;
    unsigned char* __restrict__ dst = which ? Yb : Xb;
    float* __restrict__ nrm = which ? y2 : x2;
    int* __restrict__ mn = which ? colmin : rowmin;

    const int t = threadIdx.x;
    const int r = t >> 4, c = t & 15;          // r,c in 0..15
    const int rgG = blockIdx.x;                // global row-group
    const int row = rgG * 16 + r;

    const float4 v0 = *(const float4*)(src + (size_t)row * D_ + c * 8);
    const float4 v1 = *(const float4*)(src + (size_t)row * D_ + c * 8 + 4);

    float sq = v0.x * v0.x;
    sq = fmaf(v0.y, v0.y, sq); sq = fmaf(v0.z, v0.z, sq); sq = fmaf(v0.w, v0.w, sq);
    sq = fmaf(v1.x, v1.x, sq); sq = fmaf(v1.y, v1.y, sq);
    sq = fmaf(v1.z, v1.z, sq); sq = fmaf(v1.w, v1.w, sq);
    // reduce across the 16 lanes of this row (xor masks stay in-group)
    #pragma unroll
    for (int m = 1; m < 16; m <<= 1) sq += __shfl_xor(sq, m);

    unsigned lo = 0, hi = 0;
    lo = __builtin_amdgcn_cvt_pk_fp8_f32(v0.x * SQRT2, v0.y * SQRT2, lo, false);
    lo = __builtin_amdgcn_cvt_pk_fp8_f32(v0.z * SQRT2, v0.w * SQRT2, lo, true);
    hi = __builtin_amdgcn_cvt_pk_fp8_f32(v1.x * SQRT2, v1.y * SQRT2, hi, false);
    hi = __builtin_amdgcn_cvt_pk_fp8_f32(v1.z * SQRT2, v1.w * SQRT2, hi, true);

    const int b = row >> 12;
    const int rg = (row & (N_ - 1)) >> 4;
    uint2 packed; packed.x = lo; packed.y = hi;
    // k = c*8:  (k>>5) = c>>2,  (k&31) = (c&3)*8
    *(uint2*)(dst + (size_t)b * EPB + rg * 2048 + (c >> 2) * 512
              + r * 32 + (c & 3) * 8) = packed;

    if (c == 0) {
        nrm[row] = sq;
        mn[row] = 0x7f7fffff;   // +FLT_MAX bits
    }
}

// ---------------------------------------------------------------------------
// Kernel 2: stripe-sweep MX-fp8 (K=128) MFMA chamfer. NO LDS, NO barriers.
// Block = 4 waves x 64 distinct rows = 256-row stripe (grid y = 16).
// Sweeps 4 steps of 64 cols (jc = 256-col chunk, grid x = 16).
// Per step: y2v+bfv all loaded at top (R0 memory parallelism), then TWO
// half-bursts of 8 MFMAs each through acc[4][2] (32 AGPR, zero-init),
// each followed by its fold. acc ZERO-INIT only (AGPR rule). R10 fold:
//   rm = min(rm, y2 - acc);  cm = min(cm, x2 - acc).
//   C/D layout: row = quad*4 + reg, col = l16   [m89; shape-determined]
// ---------------------------------------------------------------------------
__global__ __launch_bounds__(256, 2) void chamfer_mfma(
    const unsigned char* __restrict__ Xb, const unsigned char* __restrict__ Yb,
    const float* __restrict__ x2, const float* __restrict__ y2,
    int* __restrict__ rowmin, int* __restrict__ colmin)
{
    const int b = blockIdx.z;
    const int iT = blockIdx.y;           // 0..15  (256-row stripe)
    const int jc = blockIdx.x;           // 0..15  (256-col chunk)
    const int tid = threadIdx.x;
    const int wave = tid >> 6, lane = tid & 63;
    const int quad = lane >> 4, l16 = lane & 15;
    const int rowBase = iT * 256 + wave * 64;

    const unsigned char* __restrict__ Xp = Xb + (size_t)b * EPB;
    const unsigned char* __restrict__ Yp = Yb + (size_t)b * EPB;

    // ---- A fragments resident (4 x v8i32 = 32 VGPR), register-only build ----
    int8v af[4];
    #pragma unroll
    for (int rt = 0; rt < 4; rt++) {
        const unsigned char* ap = Xp + ((rowBase >> 4) + rt) * 2048
                                 + quad * 512 + l16 * 32;
        const int4v lo = *(const int4v*)(ap);
        const int4v hi = *(const int4v*)(ap + 16);
        af[rt] = (int8v){lo.x, lo.y, lo.z, lo.w, hi.x, hi.y, hi.z, hi.w};
    }
    float x2v[4][4];   // row = rowBase + rt*16 + quad*4 + i
    #pragma unroll
    for (int rt = 0; rt < 4; rt++)
        #pragma unroll
        for (int i = 0; i < 4; i++)
            x2v[rt][i] = x2[(size_t)b * N_ + rowBase + rt * 16 + quad * 4 + i];

    float rmin[4][4];
    #pragma unroll
    for (int rt = 0; rt < 4; rt++)
        #pragma unroll
        for (int i = 0; i < 4; i++) rmin[rt][i] = 3.0e38f;

    for (int s = 0; s < 4; ++s) {
        const int colBase = jc * 256 + s * 64;
        const int cg = colBase >> 4;               // column row-group index

        float y2v[4];
        #pragma unroll
        for (int ct = 0; ct < 4; ct++)
            y2v[ct] = y2[(size_t)b * N_ + colBase + ct * 16 + l16];

        // all 8 B-fragment loads issued before any MFMA; register-only
        int8v bfv[4];
        #pragma unroll
        for (int ct = 0; ct < 4; ct++) {
            const unsigned char* bp = Yp + (size_t)(cg + ct) * 2048
                                     + quad * 512 + l16 * 32;
            const int4v lo = *(const int4v*)(bp);
            const int4v hi = *(const int4v*)(bp + 16);
            bfv[ct] = (int8v){lo.x, lo.y, lo.z, lo.w, hi.x, hi.y, hi.z, hi.w};
        }

        // ---- two ct-halves through one 32-AGPR accumulator ----
        #pragma unroll
        for (int h = 0; h < 2; ++h) {
            f32x4 acc[4][2];
            #pragma unroll
            for (int i = 0; i < 4; i++)
                #pragma unroll
                for (int j = 0; j < 2; j++)
                    acc[i][j] = (f32x4){0.f, 0.f, 0.f, 0.f};

            #pragma unroll
            for (int rt = 0; rt < 4; rt++)
                #pragma unroll
                for (int c2 = 0; c2 < 2; c2++)
                    acc[rt][c2] = __builtin_amdgcn_mfma_scale_f32_16x16x128_f8f6f4(
                        af[rt], bfv[h * 2 + c2], acc[rt][c2],
                        0, 0,          // cbsz = fp8 e4m3 (A), blgp = fp8 e4m3 (B)
                        0, 127,        // scale A: e8m0 127 = 1.0
                        0, 127);       // scale B: e8m0 127 = 1.0

            // ---- fold this half: rmin persists; cmin emitted now ----
            float cmin[2];
            #pragma unroll
            for (int c2 = 0; c2 < 2; c2++) cmin[c2] = 3.0e38f;
            #pragma unroll
            for (int rt = 0; rt < 4; rt++)
                #pragma unroll
                for (int i = 0; i < 4; i++) {
                    const float xv = x2v[rt][i];
                    float rm = rmin[rt][i];
                    #pragma unroll
                    for (int c2 = 0; c2 < 2; c2++) {
                        const float a = acc[rt][c2][i];
                        rm = fminf(rm, y2v[h * 2 + c2] - a);
                        cmin[c2] = fminf(cmin[c2], xv - a);
                    }
                    rmin[rt][i] = rm;
                }
            #pragma unroll
            for (int c2 = 0; c2 < 2; c2++) {
                float v = cmin[c2];
                v = fminf(v, __shfl_xor(v, 16));
                v = fminf(v, __shfl_xor(v, 32));
                if (quad == 0)
                    atomicMin(&colmin[(size_t)b * N_ + colBase
                                      + (h * 2 + c2) * 16 + l16],
                              __float_as_int(v + COFF));
            }
        }
    }

    // ---- rowmin emission (once per block) ----
    #pragma unroll
    for (int rt = 0; rt < 4; rt++)
        #pragma unroll
        for (int i = 0; i < 4; i++) {
            float v = rmin[rt][i];
            #pragma unroll
            for (int m = 1; m < 16; m <<= 1) v = fminf(v, __shfl_xor(v, m));
            if (l16 == 0) {
                float c = fminf(fmaxf(x2v[rt][i] + v, 0.0f), 100.0f);
                atomicMin(&rowmin[(size_t)b * N_ + rowBase + rt * 16 + quad * 4 + i],
                          __float_as_int(c));
            }
        }
}

// ---------------------------------------------------------------------------
// Kernel 3a: partial sums, 16 blocks x 256 threads, one int4-group each.
// rowmin holds clamped values; colmin holds (min_i(x2_i - acc) + COFF):
// add y2, subtract COFF, clamp here. Deterministic tree order.
// ---------------------------------------------------------------------------
__global__ __launch_bounds__(256) void finalize1_kernel(
    const int* __restrict__ rowmin, const int* __restrict__ colmin,
    const float* __restrict__ y2, float* __restrict__ partial)
{
    const int i = blockIdx.x * 256 + threadIdx.x;   // 0..4095 int4-groups
    float s;
    {
        int4 v = ((const int4*)rowmin)[i];
        s  = __int_as_float(v.x) + __int_as_float(v.y) +
             __int_as_float(v.z) + __int_as_float(v.w);
        int4 c = ((const int4*)colmin)[i];
        float4 yv = ((const float4*)y2)[i];
        s += fminf(fmaxf(__int_as_float(c.x) - COFF + yv.x, 0.f), 100.f);
        s += fminf(fmaxf(__int_as_float(c.y) - COFF + yv.y, 0.f), 100.f);
        s += fminf(fmaxf(__int_as_float(c.z) - COFF + yv.z, 0.f), 100.f);
        s += fminf(fmaxf(__int_as_float(c.w) - COFF + yv.w, 0.f), 100.f);
    }
    #pragma unroll
    for (int m = 1; m < 64; m <<= 1) s += __shfl_xor(s, m);
    __shared__ float sm[4];
    if ((threadIdx.x & 63) == 0) sm[threadIdx.x >> 6] = s;
    __syncthreads();
    if (threadIdx.x == 0)
        partial[blockIdx.x] = sm[0] + sm[1] + sm[2] + sm[3];
}

// Kernel 3b: one wave folds the 16 partials.
__global__ __launch_bounds__(64) void finalize2_kernel(
    const float* __restrict__ partial, float* __restrict__ out)
{
    const int l = threadIdx.x;
    float s = (l < 16) ? partial[l] : 0.f;
    #pragma unroll
    for (int m = 1; m < 16; m <<= 1) s += __shfl_xor(s, m);
    if (l == 0)
        out[0] = s / ((float)B_ * (float)N_) / (float)B_;
}

extern "C" void kernel_launch(void* const* d_in, const int* in_sizes, int n_in,
                              void* d_out, int out_size, void* d_ws, size_t ws_size,
                              hipStream_t stream) {
    const float* X = (const float*)d_in[0];   // corr_pred   [B,N,D] fp32
    const float* Y = (const float*)d_in[1];   // corr_target [B,N,D] fp32

    char* ws = (char*)d_ws;
    const size_t f8_bytes = (size_t)B_ * N_ * D_;       // 2 MB each (packed fp8)
    unsigned char* Xb = (unsigned char*)ws;
    unsigned char* Yb = (unsigned char*)(ws + f8_bytes);
    char* ws2 = ws + 2 * f8_bytes;
    const size_t vec_bytes = (size_t)B_ * N_ * 4;       // 64 KB each
    float* x2      = (float*)(ws2);
    float* y2      = (float*)(ws2 + vec_bytes);
    int*   rowmin  = (int*)  (ws2 + 2 * vec_bytes);
    int*   colmin  = (int*)  (ws2 + 3 * vec_bytes);
    float* partial = (float*)(ws2 + 4 * vec_bytes);     // 16 floats
    float* out = (float*)d_out;

    prep_kernel<<<dim3(B_ * N_ / 16, 2), 256, 0, stream>>>(
        X, Y, Xb, Yb, x2, y2, rowmin, colmin);
    chamfer_mfma<<<dim3(16, N_ / 256, B_), 256, 0, stream>>>(
        Xb, Yb, x2, y2, rowmin, colmin);
    finalize1_kernel<<<16, 256, 0, stream>>>(rowmin, colmin, y2, partial);
    finalize2_kernel<<<1, 64, 0, stream>>>(partial, out);
}